// Round 1
// baseline (9311.185 us; speedup 1.0000x reference)
//
#include <hip/hip_runtime.h>

#define IN_CH 128
#define HID   256
#define BM 64
#define BN 256
#define BK 16

// ---------------- scatter layer 1: x[src] -> agg[dst] (128 ch) + degree ----------------
__global__ void scatter1_kernel(const float* __restrict__ x, const int* __restrict__ src,
                                const int* __restrict__ dst, float* __restrict__ agg,
                                float* __restrict__ deg, int E) {
    int t = threadIdx.x;
    int e = blockIdx.x * 8 + (t >> 5);
    if (e >= E) return;
    int lane = t & 31;                       // 32 lanes x float4 = 128 ch
    int s = src[e], d = dst[e];
    const float4 v = *(const float4*)(x + (size_t)s * IN_CH + lane * 4);
    float* p = agg + (size_t)d * IN_CH + lane * 4;
    atomicAdd(p + 0, v.x); atomicAdd(p + 1, v.y);
    atomicAdd(p + 2, v.z); atomicAdd(p + 3, v.w);
    if (lane == 0) atomicAdd(deg + d, 1.0f);
}

// ---------------- scatter layer 2: h[src] -> agg[dst] (256 ch) ----------------
__global__ void scatter2_kernel(const float* __restrict__ h, const int* __restrict__ src,
                                const int* __restrict__ dst, float* __restrict__ agg, int E) {
    int t = threadIdx.x;
    int e = blockIdx.x * 4 + (t >> 6);
    if (e >= E) return;
    int lane = t & 63;                       // 64 lanes x float4 = 256 ch
    int s = src[e], d = dst[e];
    const float4 v = *(const float4*)(h + (size_t)s * HID + lane * 4);
    float* p = agg + (size_t)d * HID + lane * 4;
    atomicAdd(p + 0, v.x); atomicAdd(p + 1, v.y);
    atomicAdd(p + 2, v.z); atomicAdd(p + 3, v.w);
}

__global__ void recip_kernel(const float* __restrict__ deg, float* __restrict__ recip, int N) {
    int i = blockIdx.x * 256 + threadIdx.x;
    if (i < N) recip[i] = 1.0f / fmaxf(deg[i], 1.0f);
}

// ---------------- fused concat-K GEMM ----------------
// out[i,:] = act( (agg[i,:]*recip[i]) @ Wl + xin[i,:] @ Wr + bias )
// A_eff[i,k] = k<KHALF ? agg[i*KHALF+k]*recip[i] : xin[i*KHALF + (k-KHALF)]
// B_eff[k,:] = k<KHALF ? Wl[k,:] : Wr[k-KHALF,:]    (both KHALF x 256)
template<int KHALF, bool RELU>
__global__ __launch_bounds__(256, 2)
void sage_gemm(const float* __restrict__ agg, const float* __restrict__ xin,
               const float* __restrict__ recip,
               const float* __restrict__ Wl, const float* __restrict__ Wr,
               const float* __restrict__ bias,
               float* __restrict__ out, int N) {
    __shared__ float As[BK][BM + 4];   // pad -> 2-way max (free per m136)
    __shared__ float Bs[BK][BN];

    const int t = threadIdx.x;
    const int rowBase = blockIdx.x * BM;

    // A-tile load mapping: 64 rows x 16 k, one float4/thread
    const int aRow = t >> 2;
    const int aK   = (t & 3) << 2;
    const int gRow = rowBase + aRow;
    const bool rowOK = gRow < N;
    const float rcp = rowOK ? recip[gRow] : 0.0f;

    // B-tile load mapping: 16 k-rows x 256 cols, 4 float4/thread
    const int bK = t >> 4;
    const int bC = (t & 15) << 2;

    // compute mapping: 32 col-groups x 8 row-groups, 8x8 per thread
    const int tc = t & 31;
    const int tr = t >> 5;

    float acc[8][8];
#pragma unroll
    for (int i = 0; i < 8; i++)
#pragma unroll
        for (int j = 0; j < 8; j++) acc[i][j] = 0.0f;

    const int KTOT = 2 * KHALF;
    for (int k0 = 0; k0 < KTOT; k0 += BK) {
        float4 a4 = make_float4(0.f, 0.f, 0.f, 0.f);
        if (k0 < KHALF) {
            if (rowOK) {
                a4 = *(const float4*)(agg + (size_t)gRow * KHALF + (k0 + aK));
                a4.x *= rcp; a4.y *= rcp; a4.z *= rcp; a4.w *= rcp;
            }
        } else {
            if (rowOK)
                a4 = *(const float4*)(xin + (size_t)gRow * KHALF + (k0 - KHALF + aK));
        }
        const float* Bsrc = (k0 < KHALF) ? (Wl + (size_t)k0 * BN)
                                         : (Wr + (size_t)(k0 - KHALF) * BN);
        float4 b4[4];
#pragma unroll
        for (int j = 0; j < 4; j++)
            b4[j] = *(const float4*)(Bsrc + (size_t)bK * BN + (j * 64 + bC));

        __syncthreads();
        As[aK + 0][aRow] = a4.x;
        As[aK + 1][aRow] = a4.y;
        As[aK + 2][aRow] = a4.z;
        As[aK + 3][aRow] = a4.w;
#pragma unroll
        for (int j = 0; j < 4; j++)
            *(float4*)(&Bs[bK][j * 64 + bC]) = b4[j];
        __syncthreads();

#pragma unroll
        for (int k = 0; k < BK; k++) {
            float a[8], b[8];
            *(float4*)(a)     = *(const float4*)(&As[k][tr * 8]);
            *(float4*)(a + 4) = *(const float4*)(&As[k][tr * 8 + 4]);
            *(float4*)(b)     = *(const float4*)(&Bs[k][tc * 8]);
            *(float4*)(b + 4) = *(const float4*)(&Bs[k][tc * 8 + 4]);
#pragma unroll
            for (int i = 0; i < 8; i++)
#pragma unroll
                for (int j = 0; j < 8; j++)
                    acc[i][j] = fmaf(a[i], b[j], acc[i][j]);
        }
    }

    float bvals[8];
    *(float4*)(bvals)     = *(const float4*)(bias + tc * 8);
    *(float4*)(bvals + 4) = *(const float4*)(bias + tc * 8 + 4);
#pragma unroll
    for (int i = 0; i < 8; i++) {
        int r = rowBase + tr * 8 + i;
        if (r < N) {
            float o[8];
#pragma unroll
            for (int j = 0; j < 8; j++) {
                float v = acc[i][j] + bvals[j];
                o[j] = RELU ? fmaxf(v, 0.0f) : v;
            }
            *(float4*)(out + (size_t)r * BN + tc * 8)     = *(float4*)(o);
            *(float4*)(out + (size_t)r * BN + tc * 8 + 4) = *(float4*)(o + 4);
        }
    }
}

// ---------------- decode: out[e] = dot(z[e0], z[e1]) over 256 ch ----------------
__global__ void decode_kernel(const float* __restrict__ z, const int* __restrict__ edges,
                              float* __restrict__ out, int E2) {
    int t = threadIdx.x;
    int e = blockIdx.x * 4 + (t >> 6);
    if (e >= E2) return;
    int lane = t & 63;
    int a = edges[(size_t)e * 2 + 0];
    int b = edges[(size_t)e * 2 + 1];
    const float4 va = *(const float4*)(z + (size_t)a * HID + lane * 4);
    const float4 vb = *(const float4*)(z + (size_t)b * HID + lane * 4);
    float s = va.x * vb.x + va.y * vb.y + va.z * vb.z + va.w * vb.w;
#pragma unroll
    for (int off = 32; off > 0; off >>= 1)
        s += __shfl_xor(s, off, 64);
    if (lane == 0) out[e] = s;
}

extern "C" void kernel_launch(void* const* d_in, const int* in_sizes, int n_in,
                              void* d_out, int out_size, void* d_ws, size_t ws_size,
                              hipStream_t stream) {
    const float* x    = (const float*)d_in[0];
    const int* eidx   = (const int*)d_in[1];
    const int* edges  = (const int*)d_in[2];
    const float* W1l  = (const float*)d_in[3];
    const float* b1   = (const float*)d_in[4];
    const float* W1r  = (const float*)d_in[5];
    const float* W2l  = (const float*)d_in[6];
    const float* b2   = (const float*)d_in[7];
    const float* W2r  = (const float*)d_in[8];
    float* out = (float*)d_out;

    const int N  = in_sizes[0] / IN_CH;
    const int E  = in_sizes[1] / 2;
    const int E2 = in_sizes[2] / 2;
    const int* src = eidx;
    const int* dst = eidx + E;

    // workspace layout (floats): deg[N] | recip[N] | agg[N*256] | h[N*256]
    float* deg   = (float*)d_ws;
    float* recip = deg + N;
    float* agg   = recip + N;
    float* h     = agg + (size_t)N * HID;

    hipMemsetAsync(deg, 0, (size_t)N * sizeof(float), stream);
    hipMemsetAsync(agg, 0, (size_t)N * IN_CH * sizeof(float), stream);
    scatter1_kernel<<<(E + 7) / 8, 256, 0, stream>>>(x, src, dst, agg, deg, E);
    recip_kernel<<<(N + 255) / 256, 256, 0, stream>>>(deg, recip, N);

    // h = relu(mean1 @ W1l + b1 + x @ W1r)
    sage_gemm<IN_CH, true><<<(N + BM - 1) / BM, 256, 0, stream>>>(
        agg, x, recip, W1l, W1r, b1, h, N);

    hipMemsetAsync(agg, 0, (size_t)N * HID * sizeof(float), stream);
    scatter2_kernel<<<(E + 3) / 4, 256, 0, stream>>>(h, src, dst, agg, E);

    // z = mean2 @ W2l + b2 + h @ W2r   (written in-place over h; one block owns full rows)
    sage_gemm<HID, false><<<(N + BM - 1) / BM, 256, 0, stream>>>(
        agg, h, recip, W2l, W2r, b2, h, N);

    decode_kernel<<<(E2 + 3) / 4, 256, 0, stream>>>(h, edges, out, E2);
}

// Round 2
// 1636.056 us; speedup vs baseline: 5.6912x; 5.6912x over previous
//
#include <hip/hip_runtime.h>

#define IN_CH 128
#define HID   256
#define BM 64
#define BN 256
#define BK 16

// ================= CSR build (counting sort by dst) =================
__global__ void hist_kernel(const int* __restrict__ dst, int* __restrict__ count, int E) {
    int e = blockIdx.x * 256 + threadIdx.x;
    if (e < E) atomicAdd(&count[dst[e]], 1);
}

// exclusive scan, stage 1: per-256-block scan
__global__ void scan1_kernel(const int* __restrict__ count, int* __restrict__ offs,
                             int* __restrict__ bsums, int N) {
    __shared__ int s[256];
    int t = threadIdx.x;
    int i = blockIdx.x * 256 + t;
    int v = (i < N) ? count[i] : 0;
    s[t] = v;
    __syncthreads();
    for (int d = 1; d < 256; d <<= 1) {
        int u = (t >= d) ? s[t - d] : 0;
        __syncthreads();
        s[t] += u;
        __syncthreads();
    }
    if (i < N) offs[i] = s[t] - v;          // exclusive within block
    if (t == 255) bsums[blockIdx.x] = s[255];
}

// stage 2: single-block exclusive scan of block sums (NB <= 512)
__global__ void scan2_kernel(int* __restrict__ bsums, int NB) {
    __shared__ int s[512];
    int t = threadIdx.x;
    int v = (t < NB) ? bsums[t] : 0;
    s[t] = v;
    __syncthreads();
    for (int d = 1; d < 512; d <<= 1) {
        int u = (t >= d) ? s[t - d] : 0;
        __syncthreads();
        s[t] += u;
        __syncthreads();
    }
    if (t < NB) bsums[t] = s[t] - v;
}

// stage 3: add block offsets; init cursor
__global__ void scan3_kernel(int* __restrict__ offs, const int* __restrict__ bsums,
                             int* __restrict__ cursor, int N) {
    int i = blockIdx.x * 256 + threadIdx.x;
    if (i < N) {
        int o = offs[i] + bsums[i >> 8];
        offs[i] = o;
        cursor[i] = o;
    }
}

// scatter src ids into dst-sorted adjacency
__global__ void build_nbr_kernel(const int* __restrict__ src, const int* __restrict__ dst,
                                 int* __restrict__ cursor, int* __restrict__ nbr, int E) {
    int e = blockIdx.x * 256 + threadIdx.x;
    if (e < E) {
        int d = dst[e];
        int pos = atomicAdd(&cursor[d], 1);
        nbr[pos] = src[e];
    }
}

// ================= gather-mean aggregation =================
// layer 1: 128 ch. One wave per node; 2 half-waves process 2 edges in parallel.
__global__ void agg1_kernel(const float* __restrict__ x, const int* __restrict__ nbr,
                            const int* __restrict__ offs, const int* __restrict__ count,
                            float* __restrict__ agg, int N) {
    int w = blockIdx.x * 4 + (threadIdx.x >> 6);
    if (w >= N) return;
    int lane = threadIdx.x & 63;
    int half = lane >> 5, cl = lane & 31;
    int start = offs[w], cnt = count[w];
    float4 acc = make_float4(0.f, 0.f, 0.f, 0.f);
    for (int j = half; j < cnt; j += 2) {
        int s = nbr[start + j];
        const float4 v = *(const float4*)(x + (size_t)s * IN_CH + cl * 4);
        acc.x += v.x; acc.y += v.y; acc.z += v.z; acc.w += v.w;
    }
    acc.x += __shfl_xor(acc.x, 32, 64);
    acc.y += __shfl_xor(acc.y, 32, 64);
    acc.z += __shfl_xor(acc.z, 32, 64);
    acc.w += __shfl_xor(acc.w, 32, 64);
    if (half == 0) {
        float r = 1.0f / fmaxf((float)cnt, 1.0f);
        float4 o = make_float4(acc.x * r, acc.y * r, acc.z * r, acc.w * r);
        *(float4*)(agg + (size_t)w * IN_CH + cl * 4) = o;
    }
}

// layer 2: 256 ch. One wave per node; full wave covers one edge row; unroll x2.
__global__ void agg2_kernel(const float* __restrict__ h, const int* __restrict__ nbr,
                            const int* __restrict__ offs, const int* __restrict__ count,
                            float* __restrict__ agg, int N) {
    int w = blockIdx.x * 4 + (threadIdx.x >> 6);
    if (w >= N) return;
    int lane = threadIdx.x & 63;
    int start = offs[w], cnt = count[w];
    float4 a0 = make_float4(0.f, 0.f, 0.f, 0.f);
    float4 a1 = make_float4(0.f, 0.f, 0.f, 0.f);
    int j = 0;
    for (; j + 2 <= cnt; j += 2) {
        int s0 = nbr[start + j];
        int s1 = nbr[start + j + 1];
        const float4 v0 = *(const float4*)(h + (size_t)s0 * HID + lane * 4);
        const float4 v1 = *(const float4*)(h + (size_t)s1 * HID + lane * 4);
        a0.x += v0.x; a0.y += v0.y; a0.z += v0.z; a0.w += v0.w;
        a1.x += v1.x; a1.y += v1.y; a1.z += v1.z; a1.w += v1.w;
    }
    if (j < cnt) {
        int s0 = nbr[start + j];
        const float4 v0 = *(const float4*)(h + (size_t)s0 * HID + lane * 4);
        a0.x += v0.x; a0.y += v0.y; a0.z += v0.z; a0.w += v0.w;
    }
    float r = 1.0f / fmaxf((float)cnt, 1.0f);
    float4 o = make_float4((a0.x + a1.x) * r, (a0.y + a1.y) * r,
                           (a0.z + a1.z) * r, (a0.w + a1.w) * r);
    *(float4*)(agg + (size_t)w * HID + lane * 4) = o;
}

// ================= fused concat-K GEMM =================
// out[i,:] = act( agg[i,:] @ Wl + xin[i,:] @ Wr + bias )   (agg already holds the mean)
template<int KHALF, bool RELU>
__global__ __launch_bounds__(256, 2)
void sage_gemm(const float* __restrict__ agg, const float* __restrict__ xin,
               const float* __restrict__ Wl, const float* __restrict__ Wr,
               const float* __restrict__ bias,
               float* __restrict__ out, int N) {
    __shared__ float As[BK][BM + 4];
    __shared__ float Bs[BK][BN];

    const int t = threadIdx.x;
    const int rowBase = blockIdx.x * BM;

    const int aRow = t >> 2;
    const int aK   = (t & 3) << 2;
    const int gRow = rowBase + aRow;
    const bool rowOK = gRow < N;

    const int bK = t >> 4;
    const int bC = (t & 15) << 2;

    const int tc = t & 31;
    const int tr = t >> 5;

    float acc[8][8];
#pragma unroll
    for (int i = 0; i < 8; i++)
#pragma unroll
        for (int j = 0; j < 8; j++) acc[i][j] = 0.0f;

    const int KTOT = 2 * KHALF;
    for (int k0 = 0; k0 < KTOT; k0 += BK) {
        float4 a4 = make_float4(0.f, 0.f, 0.f, 0.f);
        if (rowOK) {
            if (k0 < KHALF)
                a4 = *(const float4*)(agg + (size_t)gRow * KHALF + (k0 + aK));
            else
                a4 = *(const float4*)(xin + (size_t)gRow * KHALF + (k0 - KHALF + aK));
        }
        const float* Bsrc = (k0 < KHALF) ? (Wl + (size_t)k0 * BN)
                                         : (Wr + (size_t)(k0 - KHALF) * BN);
        float4 b4[4];
#pragma unroll
        for (int j = 0; j < 4; j++)
            b4[j] = *(const float4*)(Bsrc + (size_t)bK * BN + (j * 64 + bC));

        __syncthreads();
        As[aK + 0][aRow] = a4.x;
        As[aK + 1][aRow] = a4.y;
        As[aK + 2][aRow] = a4.z;
        As[aK + 3][aRow] = a4.w;
#pragma unroll
        for (int j = 0; j < 4; j++)
            *(float4*)(&Bs[bK][j * 64 + bC]) = b4[j];
        __syncthreads();

#pragma unroll
        for (int k = 0; k < BK; k++) {
            float a[8], b[8];
            *(float4*)(a)     = *(const float4*)(&As[k][tr * 8]);
            *(float4*)(a + 4) = *(const float4*)(&As[k][tr * 8 + 4]);
            *(float4*)(b)     = *(const float4*)(&Bs[k][tc * 8]);
            *(float4*)(b + 4) = *(const float4*)(&Bs[k][tc * 8 + 4]);
#pragma unroll
            for (int i = 0; i < 8; i++)
#pragma unroll
                for (int j = 0; j < 8; j++)
                    acc[i][j] = fmaf(a[i], b[j], acc[i][j]);
        }
    }

    float bvals[8];
    *(float4*)(bvals)     = *(const float4*)(bias + tc * 8);
    *(float4*)(bvals + 4) = *(const float4*)(bias + tc * 8 + 4);
#pragma unroll
    for (int i = 0; i < 8; i++) {
        int r = rowBase + tr * 8 + i;
        if (r < N) {
            float o[8];
#pragma unroll
            for (int j = 0; j < 8; j++) {
                float v = acc[i][j] + bvals[j];
                o[j] = RELU ? fmaxf(v, 0.0f) : v;
            }
            *(float4*)(out + (size_t)r * BN + tc * 8)     = *(float4*)(o);
            *(float4*)(out + (size_t)r * BN + tc * 8 + 4) = *(float4*)(o + 4);
        }
    }
}

// ================= decode =================
__global__ void decode_kernel(const float* __restrict__ z, const int* __restrict__ edges,
                              float* __restrict__ out, int E2) {
    int t = threadIdx.x;
    int e = blockIdx.x * 4 + (t >> 6);
    if (e >= E2) return;
    int lane = t & 63;
    int a = edges[(size_t)e * 2 + 0];
    int b = edges[(size_t)e * 2 + 1];
    const float4 va = *(const float4*)(z + (size_t)a * HID + lane * 4);
    const float4 vb = *(const float4*)(z + (size_t)b * HID + lane * 4);
    float s = va.x * vb.x + va.y * vb.y + va.z * vb.z + va.w * vb.w;
#pragma unroll
    for (int off = 32; off > 0; off >>= 1)
        s += __shfl_xor(s, off, 64);
    if (lane == 0) out[e] = s;
}

extern "C" void kernel_launch(void* const* d_in, const int* in_sizes, int n_in,
                              void* d_out, int out_size, void* d_ws, size_t ws_size,
                              hipStream_t stream) {
    const float* x    = (const float*)d_in[0];
    const int* eidx   = (const int*)d_in[1];
    const int* edges  = (const int*)d_in[2];
    const float* W1l  = (const float*)d_in[3];
    const float* b1   = (const float*)d_in[4];
    const float* W1r  = (const float*)d_in[5];
    const float* W2l  = (const float*)d_in[6];
    const float* b2   = (const float*)d_in[7];
    const float* W2r  = (const float*)d_in[8];
    float* out = (float*)d_out;

    const int N  = in_sizes[0] / IN_CH;
    const int E  = in_sizes[1] / 2;
    const int E2 = in_sizes[2] / 2;
    const int* src = eidx;
    const int* dst = eidx + E;
    const int NB = (N + 255) / 256;      // scan blocks (<=512 required)

    // workspace layout (4-byte elems):
    // count[N] | offs[N] | cursor[N] | bsums[512] | nbr[E] | agg[N*256] | h[N*256]
    int* count   = (int*)d_ws;
    int* offs    = count + N;
    int* cursor  = offs + N;
    int* bsums   = cursor + N;
    int* nbr     = bsums + 512;
    float* agg   = (float*)(nbr + E);
    float* h     = agg + (size_t)N * HID;

    // ---- CSR build ----
    hipMemsetAsync(count, 0, (size_t)N * sizeof(int), stream);
    hist_kernel<<<(E + 255) / 256, 256, 0, stream>>>(dst, count, E);
    scan1_kernel<<<NB, 256, 0, stream>>>(count, offs, bsums, N);
    scan2_kernel<<<1, 512, 0, stream>>>(bsums, NB);
    scan3_kernel<<<NB, 256, 0, stream>>>(offs, bsums, cursor, N);
    build_nbr_kernel<<<(E + 255) / 256, 256, 0, stream>>>(src, dst, cursor, nbr, E);

    // ---- layer 1 ----
    agg1_kernel<<<(N + 3) / 4, 256, 0, stream>>>(x, nbr, offs, count, agg, N);
    sage_gemm<IN_CH, true><<<(N + BM - 1) / BM, 256, 0, stream>>>(
        agg, x, W1l, W1r, b1, h, N);

    // ---- layer 2 ----
    agg2_kernel<<<(N + 3) / 4, 256, 0, stream>>>(h, nbr, offs, count, agg, N);
    sage_gemm<HID, false><<<(N + BM - 1) / BM, 256, 0, stream>>>(
        agg, h, W2l, W2r, b2, h, N);

    // ---- decode ----
    decode_kernel<<<(E2 + 3) / 4, 256, 0, stream>>>(h, edges, out, E2);
}

// Round 3
// 1047.964 us; speedup vs baseline: 8.8850x; 1.5612x over previous
//
#include <hip/hip_runtime.h>

#define IN_CH 128
#define HID   256

typedef __attribute__((ext_vector_type(8))) short bf16x8;
typedef __attribute__((ext_vector_type(4))) float f32x4;

__device__ __forceinline__ ushort f2b(float f) {
    unsigned u = __float_as_uint(f);
    unsigned r = (u + 0x7fffu + ((u >> 16) & 1u)) >> 16;
    return (ushort)r;
}
__device__ __forceinline__ float b2f(ushort h) {
    return __uint_as_float(((unsigned)h) << 16);
}

// ================= CSR build (counting sort by dst) =================
__global__ void hist_kernel(const int* __restrict__ dst, int* __restrict__ count, int E) {
    int e = blockIdx.x * 256 + threadIdx.x;
    if (e < E) atomicAdd(&count[dst[e]], 1);
}

__global__ void scan1_kernel(const int* __restrict__ count, int* __restrict__ offs,
                             int* __restrict__ bsums, int N) {
    __shared__ int s[256];
    int t = threadIdx.x;
    int i = blockIdx.x * 256 + t;
    int v = (i < N) ? count[i] : 0;
    s[t] = v;
    __syncthreads();
    for (int d = 1; d < 256; d <<= 1) {
        int u = (t >= d) ? s[t - d] : 0;
        __syncthreads();
        s[t] += u;
        __syncthreads();
    }
    if (i < N) offs[i] = s[t] - v;
    if (t == 255) bsums[blockIdx.x] = s[255];
}

__global__ void scan2_kernel(int* __restrict__ bsums, int NB) {
    __shared__ int s[512];
    int t = threadIdx.x;
    int v = (t < NB) ? bsums[t] : 0;
    s[t] = v;
    __syncthreads();
    for (int d = 1; d < 512; d <<= 1) {
        int u = (t >= d) ? s[t - d] : 0;
        __syncthreads();
        s[t] += u;
        __syncthreads();
    }
    if (t < NB) bsums[t] = s[t] - v;
}

__global__ void scan3_kernel(int* __restrict__ offs, const int* __restrict__ bsums,
                             int* __restrict__ cursor, int N) {
    int i = blockIdx.x * 256 + threadIdx.x;
    if (i < N) {
        int o = offs[i] + bsums[i >> 8];
        offs[i] = o;
        cursor[i] = o;
    }
}

__global__ void build_nbr_kernel(const int* __restrict__ src, const int* __restrict__ dst,
                                 int* __restrict__ cursor, int* __restrict__ nbr, int E) {
    int e = blockIdx.x * 256 + threadIdx.x;
    if (e < E) {
        int d = dst[e];
        int pos = atomicAdd(&cursor[d], 1);
        nbr[pos] = src[e];
    }
}

// ================= bf16 conversions =================
__global__ void cvt_kernel(const float* __restrict__ in, ushort* __restrict__ o, int n4) {
    int i = blockIdx.x * 256 + threadIdx.x;
    if (i < n4) {
        float4 v = ((const float4*)in)[i];
        ushort4 u;
        u.x = f2b(v.x); u.y = f2b(v.y); u.z = f2b(v.z); u.w = f2b(v.w);
        ((ushort4*)o)[i] = u;
    }
}

// Wt[n][k] bf16, n in [0,256), k in [0,2*KH): k<KH from Wl[k][n] else Wr[k-KH][n]
__global__ void prep_w_kernel(const float* __restrict__ Wl, const float* __restrict__ Wr,
                              ushort* __restrict__ Wt, int KH) {
    int ktot = 2 * KH;
    int idx = blockIdx.x * 256 + threadIdx.x;
    if (idx >= 256 * ktot) return;
    int n = idx / ktot, k = idx % ktot;
    float v = (k < KH) ? Wl[(size_t)k * 256 + n] : Wr[(size_t)(k - KH) * 256 + n];
    Wt[idx] = f2b(v);
}

// ================= gather-mean aggregation (bf16 in/out, f32 accum) =================
// layer 1: 128 ch; 2 half-waves x 32 lanes x 4 ch
__global__ void agg1_kernel(const ushort* __restrict__ xb, const int* __restrict__ nbr,
                            const int* __restrict__ offs, const int* __restrict__ count,
                            ushort* __restrict__ agg, int N) {
    int w = blockIdx.x * 4 + (threadIdx.x >> 6);
    if (w >= N) return;
    int lane = threadIdx.x & 63;
    int half = lane >> 5, cl = lane & 31;
    int start = offs[w], cnt = count[w];
    float ax = 0.f, ay = 0.f, az = 0.f, aw = 0.f;
    for (int j = half; j < cnt; j += 2) {
        int s = nbr[start + j];
        ushort4 v = *(const ushort4*)(xb + (size_t)s * IN_CH + cl * 4);
        ax += b2f(v.x); ay += b2f(v.y); az += b2f(v.z); aw += b2f(v.w);
    }
    ax += __shfl_xor(ax, 32, 64);
    ay += __shfl_xor(ay, 32, 64);
    az += __shfl_xor(az, 32, 64);
    aw += __shfl_xor(aw, 32, 64);
    if (half == 0) {
        float r = 1.0f / fmaxf((float)cnt, 1.0f);
        ushort4 o;
        o.x = f2b(ax * r); o.y = f2b(ay * r); o.z = f2b(az * r); o.w = f2b(aw * r);
        *(ushort4*)(agg + (size_t)w * IN_CH + cl * 4) = o;
    }
}

// layer 2: 256 ch; 64 lanes x 4 ch, 2-edge unroll
__global__ void agg2_kernel(const ushort* __restrict__ h, const int* __restrict__ nbr,
                            const int* __restrict__ offs, const int* __restrict__ count,
                            ushort* __restrict__ agg, int N) {
    int w = blockIdx.x * 4 + (threadIdx.x >> 6);
    if (w >= N) return;
    int lane = threadIdx.x & 63;
    int start = offs[w], cnt = count[w];
    float ax = 0.f, ay = 0.f, az = 0.f, aw = 0.f;
    float bx = 0.f, by = 0.f, bz = 0.f, bw = 0.f;
    int j = 0;
    for (; j + 2 <= cnt; j += 2) {
        int s0 = nbr[start + j];
        int s1 = nbr[start + j + 1];
        ushort4 v0 = *(const ushort4*)(h + (size_t)s0 * HID + lane * 4);
        ushort4 v1 = *(const ushort4*)(h + (size_t)s1 * HID + lane * 4);
        ax += b2f(v0.x); ay += b2f(v0.y); az += b2f(v0.z); aw += b2f(v0.w);
        bx += b2f(v1.x); by += b2f(v1.y); bz += b2f(v1.z); bw += b2f(v1.w);
    }
    if (j < cnt) {
        int s0 = nbr[start + j];
        ushort4 v0 = *(const ushort4*)(h + (size_t)s0 * HID + lane * 4);
        ax += b2f(v0.x); ay += b2f(v0.y); az += b2f(v0.z); aw += b2f(v0.w);
    }
    float r = 1.0f / fmaxf((float)cnt, 1.0f);
    ushort4 o;
    o.x = f2b((ax + bx) * r); o.y = f2b((ay + by) * r);
    o.z = f2b((az + bz) * r); o.w = f2b((aw + bw) * r);
    *(ushort4*)(agg + (size_t)w * HID + lane * 4) = o;
}

// ================= MFMA GEMM =================
// out[i,:] = act( Aleft[i,:] @ B[0:KH,:] + Aright[i,:] @ B[KH:,:] + bias ),  bf16 in/out
// Wt is [256][KTOT] bf16 (n-major, k contiguous). BM=64, BN=256, BK=32.
// 4 waves; wave w owns cols w*64..w*64+63 as 4x4 grid of 16x16 mfma tiles.
template<int KTOT, bool RELU>
__global__ __launch_bounds__(256, 2)
void sage_gemm_mfma(const ushort* __restrict__ Aleft, const ushort* __restrict__ Aright,
                    const ushort* __restrict__ Wt, const float* __restrict__ bias,
                    ushort* __restrict__ out, int N) {
    constexpr int KH = KTOT / 2;
    constexpr int LDA = 40;                    // 32 + 8 pad shorts -> 2-way bank alias (free)
    __shared__ ushort As[64][LDA];
    __shared__ ushort Bs[256][LDA];

    const int t = threadIdx.x;
    const int wave = t >> 6;
    const int lane = t & 63;
    const int quad = lane >> 4;
    const int l16  = lane & 15;
    const int rowBase = blockIdx.x * 64;

    // staging maps: thread -> (row, 16B chunk)
    const int sRow = t >> 2;                   // 0..63
    const int sChk = (t & 3) << 3;             // 0,8,16,24 (shorts)
    const bool aRowOK = (rowBase + sRow) < N;

    f32x4 acc[4][4];
#pragma unroll
    for (int i = 0; i < 4; i++)
#pragma unroll
        for (int j = 0; j < 4; j++) acc[i][j] = (f32x4)0.0f;

    for (int k0 = 0; k0 < KTOT; k0 += 32) {
        // global prefetch
        ulonglong2 a16 = {0ull, 0ull};         // 8 shorts
        if (aRowOK) {
            const ushort* Ap = (k0 < KH)
                ? (Aleft  + (size_t)(rowBase + sRow) * KH + (k0 + sChk))
                : (Aright + (size_t)(rowBase + sRow) * KH + (k0 - KH + sChk));
            a16 = *(const ulonglong2*)Ap;
        }
        ulonglong2 b16[4];
#pragma unroll
        for (int i = 0; i < 4; i++) {
            int n = sRow + i * 64;
            b16[i] = *(const ulonglong2*)(Wt + (size_t)n * KTOT + k0 + sChk);
        }

        __syncthreads();
        *(ulonglong2*)&As[sRow][sChk] = a16;
#pragma unroll
        for (int i = 0; i < 4; i++)
            *(ulonglong2*)&Bs[sRow + i * 64][sChk] = b16[i];
        __syncthreads();

        bf16x8 af[4], bf[4];
#pragma unroll
        for (int mt = 0; mt < 4; mt++)
            af[mt] = *(const bf16x8*)&As[mt * 16 + l16][quad * 8];
#pragma unroll
        for (int nt = 0; nt < 4; nt++)
            bf[nt] = *(const bf16x8*)&Bs[wave * 64 + nt * 16 + l16][quad * 8];
#pragma unroll
        for (int mt = 0; mt < 4; mt++)
#pragma unroll
            for (int nt = 0; nt < 4; nt++)
                acc[mt][nt] = __builtin_amdgcn_mfma_f32_16x16x32_bf16(
                    af[mt], bf[nt], acc[mt][nt], 0, 0, 0);
    }

    // epilogue: row = rowBase + mt*16 + quad*4 + reg; col = wave*64 + nt*16 + l16
    float bv[4];
#pragma unroll
    for (int nt = 0; nt < 4; nt++) bv[nt] = bias[wave * 64 + nt * 16 + l16];
#pragma unroll
    for (int mt = 0; mt < 4; mt++) {
#pragma unroll
        for (int reg = 0; reg < 4; reg++) {
            int row = rowBase + mt * 16 + quad * 4 + reg;
            if (row < N) {
#pragma unroll
                for (int nt = 0; nt < 4; nt++) {
                    float v = acc[mt][nt][reg] + bv[nt];
                    if (RELU) v = fmaxf(v, 0.0f);
                    out[(size_t)row * 256 + wave * 64 + nt * 16 + l16] = f2b(v);
                }
            }
        }
    }
}

// ================= decode: out[e] = dot(z[e0], z[e1]) bf16 in, f32 out =================
__global__ void decode_kernel(const ushort* __restrict__ z, const int* __restrict__ edges,
                              float* __restrict__ out, int E2) {
    int t = threadIdx.x;
    int e = blockIdx.x * 4 + (t >> 6);
    if (e >= E2) return;
    int lane = t & 63;
    int a = edges[(size_t)e * 2 + 0];
    int b = edges[(size_t)e * 2 + 1];
    ushort4 va = *(const ushort4*)(z + (size_t)a * HID + lane * 4);
    ushort4 vb = *(const ushort4*)(z + (size_t)b * HID + lane * 4);
    float s = b2f(va.x) * b2f(vb.x) + b2f(va.y) * b2f(vb.y)
            + b2f(va.z) * b2f(vb.z) + b2f(va.w) * b2f(vb.w);
#pragma unroll
    for (int off = 32; off > 0; off >>= 1)
        s += __shfl_xor(s, off, 64);
    if (lane == 0) out[e] = s;
}

extern "C" void kernel_launch(void* const* d_in, const int* in_sizes, int n_in,
                              void* d_out, int out_size, void* d_ws, size_t ws_size,
                              hipStream_t stream) {
    const float* x    = (const float*)d_in[0];
    const int* eidx   = (const int*)d_in[1];
    const int* edges  = (const int*)d_in[2];
    const float* W1l  = (const float*)d_in[3];
    const float* b1   = (const float*)d_in[4];
    const float* W1r  = (const float*)d_in[5];
    const float* W2l  = (const float*)d_in[6];
    const float* b2   = (const float*)d_in[7];
    const float* W2r  = (const float*)d_in[8];
    float* out = (float*)d_out;

    const int N  = in_sizes[0] / IN_CH;
    const int E  = in_sizes[1] / 2;
    const int E2 = in_sizes[2] / 2;
    const int* src = eidx;
    const int* dst = eidx + E;
    const int NB = (N + 255) / 256;

    // ws layout: ints: count[N] offs[N] cursor[N] bsums[512] nbr[E]
    // shorts:  xb[N*128] agg1b[N*128] (region reused as agg2b[N*256]) | h[N*256] | z[N*256] | Wt1 | Wt2
    int* count  = (int*)d_ws;
    int* offs   = count + N;
    int* cursor = offs + N;
    int* bsums  = cursor + N;
    int* nbr    = bsums + 512;
    ushort* xb    = (ushort*)(nbr + E);
    ushort* agg1b = xb + (size_t)N * IN_CH;
    ushort* agg2b = xb;                           // overlay: xb/agg1b dead after gemm1
    ushort* h     = agg1b + (size_t)N * IN_CH;
    ushort* z     = h + (size_t)N * HID;
    ushort* Wt1   = z + (size_t)N * HID;
    ushort* Wt2   = Wt1 + 256 * 256;

    // ---- conversions + CSR build ----
    cvt_kernel<<<((N * IN_CH / 4) + 255) / 256, 256, 0, stream>>>(x, xb, N * IN_CH / 4);
    prep_w_kernel<<<(256 * 256 + 255) / 256, 256, 0, stream>>>(W1l, W1r, Wt1, IN_CH);
    prep_w_kernel<<<(256 * 512 + 255) / 256, 256, 0, stream>>>(W2l, W2r, Wt2, HID);

    hipMemsetAsync(count, 0, (size_t)N * sizeof(int), stream);
    hist_kernel<<<(E + 255) / 256, 256, 0, stream>>>(dst, count, E);
    scan1_kernel<<<NB, 256, 0, stream>>>(count, offs, bsums, N);
    scan2_kernel<<<1, 512, 0, stream>>>(bsums, NB);
    scan3_kernel<<<NB, 256, 0, stream>>>(offs, bsums, cursor, N);
    build_nbr_kernel<<<(E + 255) / 256, 256, 0, stream>>>(src, dst, cursor, nbr, E);

    // ---- layer 1: h = relu([agg1b | xb] @ Wt1 + b1) ----
    agg1_kernel<<<(N + 3) / 4, 256, 0, stream>>>(xb, nbr, offs, count, agg1b, N);
    sage_gemm_mfma<2 * IN_CH, true><<<(N + 63) / 64, 256, 0, stream>>>(
        agg1b, xb, Wt1, b1, h, N);

    // ---- layer 2: z = [agg2b | h] @ Wt2 + b2 ----
    agg2_kernel<<<(N + 3) / 4, 256, 0, stream>>>(h, nbr, offs, count, agg2b, N);
    sage_gemm_mfma<2 * HID, false><<<(N + 63) / 64, 256, 0, stream>>>(
        agg2b, h, Wt2, b2, z, N);

    // ---- decode ----
    decode_kernel<<<(E2 + 3) / 4, 256, 0, stream>>>(z, edges, out, E2);
}

// Round 4
// 1024.274 us; speedup vs baseline: 9.0905x; 1.0231x over previous
//
#include <hip/hip_runtime.h>

#define IN_CH 128
#define HID   256

typedef __attribute__((ext_vector_type(8))) short bf16x8;
typedef __attribute__((ext_vector_type(4))) float f32x4;
typedef __attribute__((ext_vector_type(8))) unsigned short ushort8;

__device__ __forceinline__ ushort f2b(float f) {
    unsigned u = __float_as_uint(f);
    unsigned r = (u + 0x7fffu + ((u >> 16) & 1u)) >> 16;
    return (ushort)r;
}
__device__ __forceinline__ float b2f(ushort h) {
    return __uint_as_float(((unsigned)h) << 16);
}

// ================= counting-sort infrastructure =================
__global__ void hist_kernel(const int* __restrict__ key, int* __restrict__ count,
                            int E, int stride) {
    int e = blockIdx.x * 256 + threadIdx.x;
    if (e < E) atomicAdd(&count[key[(size_t)e * stride]], 1);
}

__global__ void scan1_kernel(const int* __restrict__ count, int* __restrict__ offs,
                             int* __restrict__ bsums, int N) {
    __shared__ int s[256];
    int t = threadIdx.x;
    int i = blockIdx.x * 256 + t;
    int v = (i < N) ? count[i] : 0;
    s[t] = v;
    __syncthreads();
    for (int d = 1; d < 256; d <<= 1) {
        int u = (t >= d) ? s[t - d] : 0;
        __syncthreads();
        s[t] += u;
        __syncthreads();
    }
    if (i < N) offs[i] = s[t] - v;
    if (t == 255) bsums[blockIdx.x] = s[255];
}

__global__ void scan2_kernel(int* __restrict__ bsums, int NB) {
    __shared__ int s[512];
    int t = threadIdx.x;
    int v = (t < NB) ? bsums[t] : 0;
    s[t] = v;
    __syncthreads();
    for (int d = 1; d < 512; d <<= 1) {
        int u = (t >= d) ? s[t - d] : 0;
        __syncthreads();
        s[t] += u;
        __syncthreads();
    }
    if (t < NB) bsums[t] = s[t] - v;
}

__global__ void scan3_kernel(int* __restrict__ offs, const int* __restrict__ bsums,
                             int* __restrict__ cursor, int N) {
    int i = blockIdx.x * 256 + threadIdx.x;
    if (i < N) {
        int o = offs[i] + bsums[i >> 8];
        offs[i] = o;
        cursor[i] = o;
    }
}

__global__ void build_nbr_kernel(const int* __restrict__ src, const int* __restrict__ dst,
                                 int* __restrict__ cursor, int* __restrict__ nbr, int E) {
    int e = blockIdx.x * 256 + threadIdx.x;
    if (e < E) {
        int d = dst[e];
        int pos = atomicAdd(&cursor[d], 1);
        nbr[pos] = src[e];
    }
}

// sort candidate edges by a-node; payload packs (b, original index)
__global__ void build_pairs_kernel(const int* __restrict__ edges, int* __restrict__ cursor,
                                   unsigned long long* __restrict__ pairs, int E2) {
    int e = blockIdx.x * 256 + threadIdx.x;
    if (e < E2) {
        int a = edges[(size_t)e * 2 + 0];
        int b = edges[(size_t)e * 2 + 1];
        int pos = atomicAdd(&cursor[a], 1);
        pairs[pos] = ((unsigned long long)(unsigned)b << 32) | (unsigned)e;
    }
}

// ================= bf16 conversions =================
__global__ void cvt_kernel(const float* __restrict__ in, ushort* __restrict__ o, int n4) {
    int i = blockIdx.x * 256 + threadIdx.x;
    if (i < n4) {
        float4 v = ((const float4*)in)[i];
        ushort4 u;
        u.x = f2b(v.x); u.y = f2b(v.y); u.z = f2b(v.z); u.w = f2b(v.w);
        ((ushort4*)o)[i] = u;
    }
}

__global__ void prep_w_kernel(const float* __restrict__ Wl, const float* __restrict__ Wr,
                              ushort* __restrict__ Wt, int KH) {
    int ktot = 2 * KH;
    int idx = blockIdx.x * 256 + threadIdx.x;
    if (idx >= 256 * ktot) return;
    int n = idx / ktot, k = idx % ktot;
    float v = (k < KH) ? Wl[(size_t)k * 256 + n] : Wr[(size_t)(k - KH) * 256 + n];
    Wt[idx] = f2b(v);
}

// ================= gather-mean aggregation =================
// layer 1: 128 ch = 16 lanes x 8 ch(16B). 4 groups/wave -> 4 edges in flight.
__global__ void agg1_kernel(const ushort* __restrict__ xb, const int* __restrict__ nbr,
                            const int* __restrict__ offs, const int* __restrict__ count,
                            ushort* __restrict__ agg, int N) {
    int w = blockIdx.x * 4 + (threadIdx.x >> 6);
    if (w >= N) return;
    int lane = threadIdx.x & 63;
    int grp = lane >> 4, gl = lane & 15;
    int start = offs[w], cnt = count[w];
    float acc[8];
#pragma unroll
    for (int i = 0; i < 8; i++) acc[i] = 0.0f;
    for (int j = grp; j < cnt; j += 4) {
        int s = nbr[start + j];
        ushort8 v = *(const ushort8*)(xb + (size_t)s * IN_CH + gl * 8);
#pragma unroll
        for (int i = 0; i < 8; i++) acc[i] += b2f(v[i]);
    }
#pragma unroll
    for (int i = 0; i < 8; i++) acc[i] += __shfl_xor(acc[i], 16, 64);
#pragma unroll
    for (int i = 0; i < 8; i++) acc[i] += __shfl_xor(acc[i], 32, 64);
    if (grp == 0) {
        float r = 1.0f / fmaxf((float)cnt, 1.0f);
        ushort8 o;
#pragma unroll
        for (int i = 0; i < 8; i++) o[i] = f2b(acc[i] * r);
        *(ushort8*)(agg + (size_t)w * IN_CH + gl * 8) = o;
    }
}

// layer 2: 256 ch = 32 lanes x 8 ch(16B). 2 halves x unroll 2 -> 4 edges in flight.
__global__ void agg2_kernel(const ushort* __restrict__ h, const int* __restrict__ nbr,
                            const int* __restrict__ offs, const int* __restrict__ count,
                            ushort* __restrict__ agg, int N) {
    int w = blockIdx.x * 4 + (threadIdx.x >> 6);
    if (w >= N) return;
    int lane = threadIdx.x & 63;
    int half = lane >> 5, hl = lane & 31;
    int start = offs[w], cnt = count[w];
    float a0[8], a1[8];
#pragma unroll
    for (int i = 0; i < 8; i++) { a0[i] = 0.0f; a1[i] = 0.0f; }
    int j = half;
    for (; j + 2 < cnt; j += 4) {
        int s0 = nbr[start + j];
        int s1 = nbr[start + j + 2];
        ushort8 v0 = *(const ushort8*)(h + (size_t)s0 * HID + hl * 8);
        ushort8 v1 = *(const ushort8*)(h + (size_t)s1 * HID + hl * 8);
#pragma unroll
        for (int i = 0; i < 8; i++) { a0[i] += b2f(v0[i]); a1[i] += b2f(v1[i]); }
    }
    if (j < cnt) {
        int s0 = nbr[start + j];
        ushort8 v0 = *(const ushort8*)(h + (size_t)s0 * HID + hl * 8);
#pragma unroll
        for (int i = 0; i < 8; i++) a0[i] += b2f(v0[i]);
    }
#pragma unroll
    for (int i = 0; i < 8; i++) {
        a0[i] += a1[i];
        a0[i] += __shfl_xor(a0[i], 32, 64);
    }
    if (half == 0) {
        float r = 1.0f / fmaxf((float)cnt, 1.0f);
        ushort8 o;
#pragma unroll
        for (int i = 0; i < 8; i++) o[i] = f2b(a0[i] * r);
        *(ushort8*)(agg + (size_t)w * HID + hl * 8) = o;
    }
}

// ================= MFMA GEMM =================
template<int KTOT, bool RELU>
__global__ __launch_bounds__(256, 2)
void sage_gemm_mfma(const ushort* __restrict__ Aleft, const ushort* __restrict__ Aright,
                    const ushort* __restrict__ Wt, const float* __restrict__ bias,
                    ushort* __restrict__ out, int N) {
    constexpr int KH = KTOT / 2;
    constexpr int LDA = 40;
    __shared__ ushort As[64][LDA];
    __shared__ ushort Bs[256][LDA];

    const int t = threadIdx.x;
    const int wave = t >> 6;
    const int lane = t & 63;
    const int quad = lane >> 4;
    const int l16  = lane & 15;
    const int rowBase = blockIdx.x * 64;

    const int sRow = t >> 2;
    const int sChk = (t & 3) << 3;
    const bool aRowOK = (rowBase + sRow) < N;

    f32x4 acc[4][4];
#pragma unroll
    for (int i = 0; i < 4; i++)
#pragma unroll
        for (int j = 0; j < 4; j++) acc[i][j] = (f32x4)0.0f;

    for (int k0 = 0; k0 < KTOT; k0 += 32) {
        ulonglong2 a16 = {0ull, 0ull};
        if (aRowOK) {
            const ushort* Ap = (k0 < KH)
                ? (Aleft  + (size_t)(rowBase + sRow) * KH + (k0 + sChk))
                : (Aright + (size_t)(rowBase + sRow) * KH + (k0 - KH + sChk));
            a16 = *(const ulonglong2*)Ap;
        }
        ulonglong2 b16[4];
#pragma unroll
        for (int i = 0; i < 4; i++) {
            int n = sRow + i * 64;
            b16[i] = *(const ulonglong2*)(Wt + (size_t)n * KTOT + k0 + sChk);
        }

        __syncthreads();
        *(ulonglong2*)&As[sRow][sChk] = a16;
#pragma unroll
        for (int i = 0; i < 4; i++)
            *(ulonglong2*)&Bs[sRow + i * 64][sChk] = b16[i];
        __syncthreads();

        bf16x8 af[4], bf[4];
#pragma unroll
        for (int mt = 0; mt < 4; mt++)
            af[mt] = *(const bf16x8*)&As[mt * 16 + l16][quad * 8];
#pragma unroll
        for (int nt = 0; nt < 4; nt++)
            bf[nt] = *(const bf16x8*)&Bs[wave * 64 + nt * 16 + l16][quad * 8];
#pragma unroll
        for (int mt = 0; mt < 4; mt++)
#pragma unroll
            for (int nt = 0; nt < 4; nt++)
                acc[mt][nt] = __builtin_amdgcn_mfma_f32_16x16x32_bf16(
                    af[mt], bf[nt], acc[mt][nt], 0, 0, 0);
    }

    float bv[4];
#pragma unroll
    for (int nt = 0; nt < 4; nt++) bv[nt] = bias[wave * 64 + nt * 16 + l16];
#pragma unroll
    for (int mt = 0; mt < 4; mt++) {
#pragma unroll
        for (int reg = 0; reg < 4; reg++) {
            int row = rowBase + mt * 16 + quad * 4 + reg;
            if (row < N) {
#pragma unroll
                for (int nt = 0; nt < 4; nt++) {
                    float v = acc[mt][nt][reg] + bv[nt];
                    if (RELU) v = fmaxf(v, 0.0f);
                    out[(size_t)row * 256 + wave * 64 + nt * 16 + l16] = f2b(v);
                }
            }
        }
    }
}

// ================= decode v2: one wave per a-node over a-sorted pairs =================
__global__ void decode2_kernel(const ushort* __restrict__ z,
                               const unsigned long long* __restrict__ pairs,
                               const int* __restrict__ offs, const int* __restrict__ count,
                               float* __restrict__ out, int N) {
    int a = blockIdx.x * 4 + (threadIdx.x >> 6);
    if (a >= N) return;
    int cnt = count[a];
    if (cnt == 0) return;
    int lane = threadIdx.x & 63;
    int half = lane >> 5, hl = lane & 31;
    int start = offs[a];

    // a-row into registers: 32 lanes x 8 ch (both halves hold a copy)
    float ar[8];
    {
        ushort8 va = *(const ushort8*)(z + (size_t)a * HID + hl * 8);
#pragma unroll
        for (int i = 0; i < 8; i++) ar[i] = b2f(va[i]);
    }

    int j = half;
    for (; j + 2 < cnt; j += 4) {          // this half's edges: half, half+2, ...
        unsigned long long p0 = pairs[start + j];
        unsigned long long p1 = pairs[start + j + 2];
        int b0 = (int)(p0 >> 32), e0 = (int)(p0 & 0xffffffffu);
        int b1 = (int)(p1 >> 32), e1 = (int)(p1 & 0xffffffffu);
        ushort8 v0 = *(const ushort8*)(z + (size_t)b0 * HID + hl * 8);
        ushort8 v1 = *(const ushort8*)(z + (size_t)b1 * HID + hl * 8);
        float s0 = 0.f, s1 = 0.f;
#pragma unroll
        for (int i = 0; i < 8; i++) { s0 = fmaf(ar[i], b2f(v0[i]), s0);
                                      s1 = fmaf(ar[i], b2f(v1[i]), s1); }
#pragma unroll
        for (int off = 1; off < 32; off <<= 1) { s0 += __shfl_xor(s0, off, 64);
                                                 s1 += __shfl_xor(s1, off, 64); }
        if (hl == 0) { out[e0] = s0; out[e1] = s1; }
    }
    if (j < cnt) {
        unsigned long long p0 = pairs[start + j];
        int b0 = (int)(p0 >> 32), e0 = (int)(p0 & 0xffffffffu);
        ushort8 v0 = *(const ushort8*)(z + (size_t)b0 * HID + hl * 8);
        float s0 = 0.f;
#pragma unroll
        for (int i = 0; i < 8; i++) s0 = fmaf(ar[i], b2f(v0[i]), s0);
#pragma unroll
        for (int off = 1; off < 32; off <<= 1) s0 += __shfl_xor(s0, off, 64);
        if (hl == 0) out[e0] = s0;
    }
}

extern "C" void kernel_launch(void* const* d_in, const int* in_sizes, int n_in,
                              void* d_out, int out_size, void* d_ws, size_t ws_size,
                              hipStream_t stream) {
    const float* x    = (const float*)d_in[0];
    const int* eidx   = (const int*)d_in[1];
    const int* edges  = (const int*)d_in[2];
    const float* W1l  = (const float*)d_in[3];
    const float* b1   = (const float*)d_in[4];
    const float* W1r  = (const float*)d_in[5];
    const float* W2l  = (const float*)d_in[6];
    const float* b2   = (const float*)d_in[7];
    const float* W2r  = (const float*)d_in[8];
    float* out = (float*)d_out;

    const int N  = in_sizes[0] / IN_CH;
    const int E  = in_sizes[1] / 2;
    const int E2 = in_sizes[2] / 2;
    const int* src = eidx;
    const int* dst = eidx + E;
    const int NB = (N + 255) / 256;

    // ws: ints count[N] offs[N] cursor[N] bsums[512] nbr[E] | pairs[E2] u64 | shorts...
    int* count  = (int*)d_ws;
    int* offs   = count + N;
    int* cursor = offs + N;
    int* bsums  = cursor + N;
    int* nbr    = bsums + 512;
    size_t intWords = (size_t)3 * N + 512 + E;
    intWords = (intWords + 1) & ~(size_t)1;                 // 8B align
    unsigned long long* pairs = (unsigned long long*)((int*)d_ws + intWords);
    ushort* xb    = (ushort*)(pairs + E2);
    ushort* agg1b = xb + (size_t)N * IN_CH;
    ushort* agg2b = xb;                                     // overlay after gemm1
    ushort* h     = agg1b + (size_t)N * IN_CH;
    ushort* z     = h + (size_t)N * HID;
    ushort* Wt1   = z + (size_t)N * HID;
    ushort* Wt2   = Wt1 + 256 * 256;

    // ---- conversions ----
    cvt_kernel<<<((N * IN_CH / 4) + 255) / 256, 256, 0, stream>>>(x, xb, N * IN_CH / 4);
    prep_w_kernel<<<(256 * 256 + 255) / 256, 256, 0, stream>>>(W1l, W1r, Wt1, IN_CH);
    prep_w_kernel<<<(256 * 512 + 255) / 256, 256, 0, stream>>>(W2l, W2r, Wt2, HID);

    // ---- graph CSR (sort by dst) ----
    hipMemsetAsync(count, 0, (size_t)N * sizeof(int), stream);
    hist_kernel<<<(E + 255) / 256, 256, 0, stream>>>(dst, count, E, 1);
    scan1_kernel<<<NB, 256, 0, stream>>>(count, offs, bsums, N);
    scan2_kernel<<<1, 512, 0, stream>>>(bsums, NB);
    scan3_kernel<<<NB, 256, 0, stream>>>(offs, bsums, cursor, N);
    build_nbr_kernel<<<(E + 255) / 256, 256, 0, stream>>>(src, dst, cursor, nbr, E);

    // ---- layer 1 ----
    agg1_kernel<<<(N + 3) / 4, 256, 0, stream>>>(xb, nbr, offs, count, agg1b, N);
    sage_gemm_mfma<2 * IN_CH, true><<<(N + 63) / 64, 256, 0, stream>>>(
        agg1b, xb, Wt1, b1, h, N);

    // ---- layer 2 ----
    agg2_kernel<<<(N + 3) / 4, 256, 0, stream>>>(h, nbr, offs, count, agg2b, N);
    sage_gemm_mfma<2 * HID, false><<<(N + 63) / 64, 256, 0, stream>>>(
        agg2b, h, Wt2, b2, z, N);

    // ---- decode: sort candidate edges by a (reuses count/offs/cursor, dead after agg2) ----
    hipMemsetAsync(count, 0, (size_t)N * sizeof(int), stream);
    hist_kernel<<<(E2 + 255) / 256, 256, 0, stream>>>(edges, count, E2, 2);
    scan1_kernel<<<NB, 256, 0, stream>>>(count, offs, bsums, N);
    scan2_kernel<<<1, 512, 0, stream>>>(bsums, NB);
    scan3_kernel<<<NB, 256, 0, stream>>>(offs, bsums, cursor, N);
    build_pairs_kernel<<<(E2 + 255) / 256, 256, 0, stream>>>(edges, cursor, pairs, E2);

    decode2_kernel<<<(N + 3) / 4, 256, 0, stream>>>(z, pairs, offs, count, out, N);
}